// Round 2
// baseline (791.647 us; speedup 1.0000x reference)
//
#include <hip/hip_runtime.h>
#include <hip/hip_bf16.h>

// LSTM: B=1024, T=512, I=4, H=128, O=4. Gate order i,f,g,o (PyTorch).
// out[b][o] = (h_T @ W_fc^T + b_fc)
//
// Strategy: batch-parallel blocks (16 rows/block, 64 blocks), full T-loop
// on-chip. Recurrent GEMM via mfma_f32_16x16x32_bf16 with K extended to 160
// to fuse the x-projection (W_ih, I=4) as a 5th K-chunk. W fragments held in
// registers for the whole kernel. A-tile (h|x|0) double-buffered in LDS.
// Wave w owns hidden columns 16w..16w+15 for all four gates -> i,f,g,o for a
// (row,k) pair are in one thread's accs -> in-register c/h update.

#define Tlen 512
#define Iin  4
#define Hdim 128
#define Odim 4

typedef __attribute__((ext_vector_type(8))) short bf16x8;
typedef __attribute__((ext_vector_type(4))) short short4v;
typedef __attribute__((ext_vector_type(4))) float f32x4;

__device__ __forceinline__ short f2bf(float f) {
  union { float f; unsigned u; } v; v.f = f;
  unsigned u = v.u;
  return (short)((u + 0x7FFFu + ((u >> 16) & 1u)) >> 16);  // RNE
}
__device__ __forceinline__ float sigm(float x) {
  return 1.0f / (1.0f + __expf(-x));
}
__device__ __forceinline__ float tanh_(float x) {
  float e = __expf(2.0f * x);
  return 1.0f - 2.0f / (e + 1.0f);
}

__global__ __launch_bounds__(512, 2) void lstm_kernel(
    const float* __restrict__ x, const float* __restrict__ W_ih,
    const float* __restrict__ W_hh, const float* __restrict__ b_ih,
    const float* __restrict__ b_hh, const float* __restrict__ W_fc,
    const float* __restrict__ b_fc, float* __restrict__ out) {
  // A-tile: 16 rows x 168 K-elems (only 0..159 used; 132..159 stay zero).
  // Row stride 168 shorts = 336 B = 21*16 B (aligned for b128, conflict-benign).
  __shared__ alignas(16) short Albuf[2][16][168];
  __shared__ float hfin[16][Hdim];

  const int tid  = threadIdx.x;
  const int wid  = tid >> 6;        // wave 0..7
  const int lane = tid & 63;
  const int m16  = lane & 15;       // A row / D col within tile
  const int grp  = lane >> 4;       // k-group 0..3
  const int col  = wid * 16 + m16;  // hidden index owned (0..127)
  const int bbase = blockIdx.x * 16;

  // ---- W fragments into registers (once) ----
  // B-frag lane l elem e = B[k = kc*32 + (l>>4)*8 + e][n = l&15], B[k][n] = W[g][k]
  bf16x8 Wf[4][5];
  float bsc[4];
#pragma unroll
  for (int q = 0; q < 4; ++q) {
    const int g = q * 128 + col;  // gate row: q selects i/f/g/o block
#pragma unroll
    for (int kc = 0; kc < 4; ++kc) {
      const float* src = W_hh + (size_t)g * Hdim + kc * 32 + grp * 8;
      bf16x8 w;
#pragma unroll
      for (int e = 0; e < 8; ++e) w[e] = f2bf(src[e]);
      Wf[q][kc] = w;
    }
    bf16x8 w4 = {0, 0, 0, 0, 0, 0, 0, 0};  // 5th chunk: [W_ih(4)|0...]
    if (grp == 0) {
#pragma unroll
      for (int e = 0; e < 4; ++e) w4[e] = f2bf(W_ih[g * Iin + e]);
    }
    Wf[q][4] = w4;
    bsc[q] = b_ih[g] + b_hh[g];
  }

  // ---- init LDS: zeros (h0=0, pad=0), then x(t=0) into buf0 ----
  for (int i = tid; i < 2 * 16 * 168; i += 512) ((short*)Albuf)[i] = 0;
  __syncthreads();
  if (wid == 0 && lane < 16) {
    const float* xs = x + (size_t)(bbase + m16) * (Tlen * Iin);
    short4v xv;
#pragma unroll
    for (int e = 0; e < 4; ++e) xv[e] = f2bf(xs[e]);
    *(short4v*)&Albuf[0][m16][128] = xv;
  }
  __syncthreads();

  float c4[4] = {0.f, 0.f, 0.f, 0.f};
  float hl[4] = {0.f, 0.f, 0.f, 0.f};

  for (int t = 0; t < Tlen; ++t) {
    const int cur = t & 1, nxt = cur ^ 1;

    // prefetch x(t+1) early (hidden under MFMA+VALU)
    float xf0 = 0.f, xf1 = 0.f, xf2 = 0.f, xf3 = 0.f;
    const bool doX = (wid == 0) && (lane < 16) && (t + 1 < Tlen);
    if (doX) {
      const float* xs = x + (size_t)(bbase + m16) * (Tlen * Iin) + (t + 1) * Iin;
      xf0 = xs[0]; xf1 = xs[1]; xf2 = xs[2]; xf3 = xs[3];
    }

    // A fragments: lane l elem e = A[m = l&15][k = kc*32 + (l>>4)*8 + e]
    bf16x8 a[5];
#pragma unroll
    for (int kc = 0; kc < 5; ++kc)
      a[kc] = *(const bf16x8*)&Albuf[cur][m16][kc * 32 + grp * 8];

    // gates = bias + [h|x|0] @ [W_hh|W_ih|0]^T
    f32x4 acc[4];
#pragma unroll
    for (int q = 0; q < 4; ++q) {
      f32x4 c0;
      c0[0] = bsc[q]; c0[1] = bsc[q]; c0[2] = bsc[q]; c0[3] = bsc[q];
      acc[q] = __builtin_amdgcn_mfma_f32_16x16x32_bf16(a[0], Wf[q][0], c0, 0, 0, 0);
#pragma unroll
      for (int kc = 1; kc < 5; ++kc)
        acc[q] = __builtin_amdgcn_mfma_f32_16x16x32_bf16(a[kc], Wf[q][kc], acc[q], 0, 0, 0);
    }

    // elementwise: rows grp*4+r, col fixed. i,f,g,o all local.
#pragma unroll
    for (int r = 0; r < 4; ++r) {
      float ig = sigm(acc[0][r]);
      float fg = sigm(acc[1][r]);
      float gg = tanh_(acc[2][r]);
      float og = sigm(acc[3][r]);
      float c = fg * c4[r] + ig * gg;
      c4[r] = c;
      float h = og * tanh_(c);
      hl[r] = h;
      Albuf[nxt][grp * 4 + r][col] = f2bf(h);
    }
    if (doX) {
      short4v xv;
      xv[0] = f2bf(xf0); xv[1] = f2bf(xf1); xv[2] = f2bf(xf2); xv[3] = f2bf(xf3);
      *(short4v*)&Albuf[nxt][m16][128] = xv;
    }
    __syncthreads();
  }

  // ---- final FC: out = h_T @ W_fc^T + b_fc ----
#pragma unroll
  for (int r = 0; r < 4; ++r) hfin[grp * 4 + r][col] = hl[r];
  __syncthreads();
  if (tid < 64) {
    const int row = tid >> 2, o = tid & 3;
    float s = b_fc[o];
#pragma unroll 8
    for (int k = 0; k < Hdim; ++k) s += hfin[row][k] * W_fc[o * Hdim + k];
    out[(size_t)(bbase + row) * Odim + o] = s;
  }
}

extern "C" void kernel_launch(void* const* d_in, const int* in_sizes, int n_in,
                              void* d_out, int out_size, void* d_ws, size_t ws_size,
                              hipStream_t stream) {
  const float* x    = (const float*)d_in[0];
  const float* W_ih = (const float*)d_in[1];
  const float* W_hh = (const float*)d_in[2];
  const float* b_ih = (const float*)d_in[3];
  const float* b_hh = (const float*)d_in[4];
  const float* W_fc = (const float*)d_in[5];
  const float* b_fc = (const float*)d_in[6];
  float* out = (float*)d_out;
  lstm_kernel<<<64, 512, 0, stream>>>(x, W_ih, W_hh, b_ih, b_hh, W_fc, b_fc, out);
}

// Round 3
// 425.984 us; speedup vs baseline: 1.8584x; 1.8584x over previous
//
#include <hip/hip_runtime.h>
#include <hip/hip_bf16.h>

// LSTM: B=1024, T=512, I=4, H=128, O=4. Gate order i,f,g,o (PyTorch).
// out = h_T @ W_fc^T + b_fc
//
// Decomposition: 64 blocks x 16 batch rows, full T-loop on-chip (recurrence
// couples all of H -> one block owns a batch slice end-to-end).
// Per timestep: gates(16x512) = [h|x] @ [W_hh|W_ih]^T via mfma_f32_16x16x32_bf16
// with K extended 128->160 to fuse the x-projection. OPERANDS SWAPPED vs r0:
// A = weight tile (M=gate cols), B = [h|x]^T (N=batch rows). D: col(lane&15)=batch,
// row(grp*4+r)=gate col -> each thread owns 4 CONSECUTIVE hidden cols of one
// batch row for all 4 gates -> in-register c/h update, packed b64 h-write.
// Weights pre-scaled by log2(e) (2*log2e for g-gate) so activations use native
// v_exp_f32/v_rcp_f32: sigmoid = rcp(1+exp2(-x)), 3 instrs.

#define Tlen 512
#define Iin  4
#define Hdim 128
#define Odim 4

typedef __attribute__((ext_vector_type(8))) short bf16x8;
typedef __attribute__((ext_vector_type(4))) float f32x4;
typedef __attribute__((ext_vector_type(2))) unsigned uint2v;

__device__ __forceinline__ short f2bf(float f) {
  union { float f; unsigned u; } v; v.f = f;
  unsigned u = v.u;
  return (short)((u + 0x7FFFu + ((u >> 16) & 1u)) >> 16);  // RNE
}
__device__ __forceinline__ unsigned cvt_pk_bf16(float lo, float hi) {
  unsigned r;
  asm("v_cvt_pk_bf16_f32 %0, %1, %2" : "=v"(r) : "v"(lo), "v"(hi));
  return r;
}
__device__ __forceinline__ float ex2(float x) { return __builtin_amdgcn_exp2f(x); }
__device__ __forceinline__ float rcp_(float x) { return __builtin_amdgcn_rcpf(x); }

__global__ __launch_bounds__(512, 2) void lstm_kernel(
    const float* __restrict__ x, const float* __restrict__ W_ih,
    const float* __restrict__ W_hh, const float* __restrict__ b_ih,
    const float* __restrict__ b_hh, const float* __restrict__ W_fc,
    const float* __restrict__ b_fc, float* __restrict__ out) {
  // LDS tile: [batch row n][k]: k 0..127 = h (bf16), 128..131 = x, 132..159 zero pad.
  // Row stride 168 shorts = 336 B = 21*16B (b128-aligned; 2-way bank alias only).
  __shared__ alignas(16) short Albuf[2][16][168];
  __shared__ float hfin[16][Hdim];

  const int tid  = threadIdx.x;
  const int wid  = tid >> 6;        // wave 0..7 -> hidden cols wid*16..+15
  const int lane = tid & 63;
  const int m16  = lane & 15;       // batch row (N dim) / weight row within tile
  const int grp  = lane >> 4;       // k-group 0..3
  const int bbase = blockIdx.x * 16;
  const float L2E = 1.4426950408889634f;

  // ---- weight fragments (A-operand), pre-scaled, in registers for whole kernel ----
  // A-frag lane l elem e = A[m = l&15][k = kc*32 + (l>>4)*8 + e], A[m][k] = sc*W[g(m)][k]
  bf16x8 Wf[4][5];
  f32x4  c0[4];  // bias in C-operand: c0[q][r] for gate col grp*4+r
#pragma unroll
  for (int q = 0; q < 4; ++q) {
    const float sc = (q == 2) ? 2.0f * L2E : L2E;   // g-gate: tanh needs 2x
    const int gm = q * 128 + wid * 16 + m16;        // weight row this lane loads
#pragma unroll
    for (int kc = 0; kc < 4; ++kc) {
      const float* src = W_hh + (size_t)gm * Hdim + kc * 32 + grp * 8;
      bf16x8 w;
#pragma unroll
      for (int e = 0; e < 8; ++e) w[e] = f2bf(src[e] * sc);
      Wf[q][kc] = w;
    }
    bf16x8 w4 = {0, 0, 0, 0, 0, 0, 0, 0};  // 5th K-chunk: [W_ih(4)|0...]
    if (grp == 0) {
#pragma unroll
      for (int e = 0; e < 4; ++e) w4[e] = f2bf(W_ih[gm * Iin + e] * sc);
    }
    Wf[q][4] = w4;
#pragma unroll
    for (int r = 0; r < 4; ++r) {
      const int gr = q * 128 + wid * 16 + grp * 4 + r;  // this thread's gate col
      c0[q][r] = (b_ih[gr] + b_hh[gr]) * sc;
    }
  }

  // ---- init LDS (h0 = 0, pads = 0), stage x(t=0) ----
  for (int i = tid; i < 2 * 16 * 168; i += 512) ((short*)Albuf)[i] = 0;
  __syncthreads();
  if (wid == 0 && lane < 16) {
    const float* xs = x + (size_t)(bbase + m16) * (Tlen * Iin);
    uint2v p;
    p[0] = cvt_pk_bf16(xs[0], xs[1]);
    p[1] = cvt_pk_bf16(xs[2], xs[3]);
    *(uint2v*)&Albuf[0][m16][128] = p;
  }
  __syncthreads();

  float c4[4] = {0.f, 0.f, 0.f, 0.f};
  float hl[4] = {0.f, 0.f, 0.f, 0.f};

  for (int t = 0; t < Tlen; ++t) {
    const int cur = t & 1, nxt = cur ^ 1;

    // prefetch x(t+1) (global latency hides under MFMA+activations)
    f32x4 xv = {0.f, 0.f, 0.f, 0.f};
    const bool doX = (wid == 0) && (lane < 16) && (t + 1 < Tlen);
    if (doX)
      xv = *(const f32x4*)(x + (size_t)(bbase + m16) * (Tlen * Iin) + (t + 1) * Iin);

    // B fragments (h^T): lane l elem e = B[k = kc*32 + (l>>4)*8 + e][n = l&15]
    bf16x8 b[5];
#pragma unroll
    for (int kc = 0; kc < 5; ++kc)
      b[kc] = *(const bf16x8*)&Albuf[cur][m16][kc * 32 + grp * 8];

    // gates(scaled) = bias + W_scaled @ [h|x]^T
    f32x4 acc[4];
#pragma unroll
    for (int q = 0; q < 4; ++q)
      acc[q] = __builtin_amdgcn_mfma_f32_16x16x32_bf16(Wf[q][0], b[0], c0[q], 0, 0, 0);
#pragma unroll
    for (int kc = 1; kc < 5; ++kc)
#pragma unroll
      for (int q = 0; q < 4; ++q)
        acc[q] = __builtin_amdgcn_mfma_f32_16x16x32_bf16(Wf[q][kc], b[kc], acc[q], 0, 0, 0);

    // elementwise: batch row m16, hidden cols wid*16+grp*4+r. Pre-scaled domain:
    // sigm(x) = rcp(1+exp2(-xs)); tanh(x) = 2*rcp(1+exp2(-xs)) - 1 (xs has the 2x).
#pragma unroll
    for (int r = 0; r < 4; ++r) {
      float ig = rcp_(1.0f + ex2(-acc[0][r]));
      float fg = rcp_(1.0f + ex2(-acc[1][r]));
      float gt = __builtin_fmaf(2.0f, rcp_(1.0f + ex2(-acc[2][r])), -1.0f);
      float og = rcp_(1.0f + ex2(-acc[3][r]));
      float c  = __builtin_fmaf(fg, c4[r], ig * gt);
      c4[r] = c;
      float tc = __builtin_fmaf(2.0f, rcp_(1.0f + ex2(-2.8853900817779268f * c)), -1.0f);
      hl[r] = og * tc;
    }
    // packed h-write: 4 consecutive hidden cols -> one ds_write_b64
    {
      uint2v p;
      p[0] = cvt_pk_bf16(hl[0], hl[1]);
      p[1] = cvt_pk_bf16(hl[2], hl[3]);
      *(uint2v*)&Albuf[nxt][m16][wid * 16 + grp * 4] = p;
    }
    if (doX) {
      uint2v p;
      p[0] = cvt_pk_bf16(xv[0], xv[1]);
      p[1] = cvt_pk_bf16(xv[2], xv[3]);
      *(uint2v*)&Albuf[nxt][m16][128] = p;
    }
    __syncthreads();
  }

  // ---- final FC: out = h_T @ W_fc^T + b_fc ----
  {
    f32x4 hv;
    hv[0] = hl[0]; hv[1] = hl[1]; hv[2] = hl[2]; hv[3] = hl[3];
    *(f32x4*)&hfin[m16][wid * 16 + grp * 4] = hv;
  }
  __syncthreads();
  if (tid < 64) {
    const int row = tid >> 2, o = tid & 3;
    float s = b_fc[o];
#pragma unroll 8
    for (int k = 0; k < Hdim; ++k) s += hfin[row][k] * W_fc[o * Hdim + k];
    out[(size_t)(bbase + row) * Odim + o] = s;
  }
}

extern "C" void kernel_launch(void* const* d_in, const int* in_sizes, int n_in,
                              void* d_out, int out_size, void* d_ws, size_t ws_size,
                              hipStream_t stream) {
  const float* x    = (const float*)d_in[0];
  const float* W_ih = (const float*)d_in[1];
  const float* W_hh = (const float*)d_in[2];
  const float* b_ih = (const float*)d_in[3];
  const float* b_hh = (const float*)d_in[4];
  const float* W_fc = (const float*)d_in[5];
  const float* b_fc = (const float*)d_in[6];
  float* out = (float*)d_out;
  lstm_kernel<<<64, 512, 0, stream>>>(x, W_ih, W_hh, b_ih, b_hh, W_fc, b_fc, out);
}

// Round 5
// 400.398 us; speedup vs baseline: 1.9772x; 1.0639x over previous
//
#include <hip/hip_runtime.h>
#include <hip/hip_bf16.h>

// LSTM: B=1024, T=512, I=4, H=128, O=4. Gate order i,f,g,o (PyTorch).
// out = h_T @ W_fc^T + b_fc
//
// 64 blocks x 16 batch rows, full T-loop on-chip. Per step:
// gates(512x16) = W_scaled @ [h]^T via mfma_f32_16x16x32_bf16 (4 K-chunks)
// + x-projection as a register-only MFMA computed at the END of the previous
// step (acc init = bias + Wx@x(t)) so it drains during the barrier wait.
// A = weights (registers, whole kernel), B = h^T read from LDS double-buffer.
// D: col(lane&15)=batch row, row(grp*4+r)=gate col -> each thread owns 4
// consecutive hidden cols of one batch row for all 4 gates -> in-register
// c/h update, one packed ds_write_b64 for h.
// Weights pre-scaled by log2e (2*log2e for g-gate): sigmoid = rcp(1+exp2(-x)).
// Activations interleaved per gate-chain so trans ops overlap MFMA latency.
//
// NOTE (round-4 post-mortem): no templates, no array-reference params, no
// VGPR cap — round 4's NaN is attributed to the template/reference-param
// structure under a 128-VGPR launch_bounds cap; all state here is named
// loop-carried variables, addressing is the round-3-proven runtime-cur form.

#define Tlen 512
#define Iin  4
#define Hdim 128
#define Odim 4

typedef __attribute__((ext_vector_type(8))) short bf16x8;
typedef __attribute__((ext_vector_type(4))) float f32x4;
typedef __attribute__((ext_vector_type(2))) unsigned uint2v;
typedef __attribute__((ext_vector_type(4))) unsigned uint4v;

static __device__ __forceinline__ short f2bf(float f) {
  union { float f; unsigned u; } v; v.f = f;
  unsigned u = v.u;
  return (short)((u + 0x7FFFu + ((u >> 16) & 1u)) >> 16);  // RNE
}
static __device__ __forceinline__ unsigned cvt_pk_bf16(float lo, float hi) {
  unsigned r;
  asm("v_cvt_pk_bf16_f32 %0, %1, %2" : "=v"(r) : "v"(lo), "v"(hi));
  return r;
}
static __device__ __forceinline__ float ex2(float x) { return __builtin_amdgcn_exp2f(x); }
static __device__ __forceinline__ float rcp_(float x) { return __builtin_amdgcn_rcpf(x); }

#define MFMA __builtin_amdgcn_mfma_f32_16x16x32_bf16

__global__ __launch_bounds__(512) void lstm_kernel(
    const float* __restrict__ x, const float* __restrict__ W_ih,
    const float* __restrict__ W_hh, const float* __restrict__ b_ih,
    const float* __restrict__ b_hh, const float* __restrict__ W_fc,
    const float* __restrict__ b_fc, float* __restrict__ out) {
  // h double-buffer: [buf][batch row][k]; row stride 168 shorts = 336 B
  // (b128-aligned; measured-benign banking). Cols 0..127 = h, rest unused/0.
  __shared__ alignas(16) short Albuf[2][16][168];
  __shared__ float hfin[16][Hdim];

  const int tid  = threadIdx.x;
  const int wid  = tid >> 6;    // wave 0..7 -> hidden cols wid*16..+15
  const int lane = tid & 63;
  const int m16  = lane & 15;   // batch row / weight row within tile
  const int grp  = lane >> 4;   // k-group 0..3
  const int bbase = blockIdx.x * 16;
  const float L2E = 1.4426950408889634f;

  // ---- weight fragments (A-operand), pre-scaled, registers for whole kernel ----
  // A-frag lane l elem e = A[m = l&15][k = kc*32 + (l>>4)*8 + e]
  bf16x8 Wf[4][4];
  bf16x8 Wx[4];
  f32x4  c0v[4];
#pragma unroll
  for (int q = 0; q < 4; ++q) {
    const float sc = (q == 2) ? 2.0f * L2E : L2E;   // g-gate: tanh needs 2x
    const int gm = q * 128 + wid * 16 + m16;        // weight row this lane holds
#pragma unroll
    for (int kc = 0; kc < 4; ++kc) {
      const float* src = W_hh + (size_t)gm * Hdim + kc * 32 + grp * 8;
      bf16x8 w;
#pragma unroll
      for (int e = 0; e < 8; ++e) w[e] = f2bf(src[e] * sc);
      Wf[q][kc] = w;
    }
    bf16x8 w4 = {0, 0, 0, 0, 0, 0, 0, 0};  // x-chunk A: [W_ih(4)|0...] at k=0..7
    if (grp == 0) {
#pragma unroll
      for (int e = 0; e < 4; ++e) w4[e] = f2bf(W_ih[gm * Iin + e] * sc);
    }
    Wx[q] = w4;
#pragma unroll
    for (int r = 0; r < 4; ++r) {
      const int gr = q * 128 + wid * 16 + grp * 4 + r;  // this thread's gate col
      c0v[q][r] = (b_ih[gr] + b_hh[gr]) * sc;
    }
  }

  // ---- zero h buffers ----
  for (int i = tid; i < 2 * 16 * 168; i += 512) ((short*)Albuf)[i] = 0;

  const float* xrow = x + (size_t)(bbase + m16) * (Tlen * Iin);

  // ---- acc = bias + Wx @ x(0) (register-only MFMAs, no LDS dependency) ----
  // B-frag: lane l elem e = B[k=(l>>4)*8+e][n=l&15]; only grp==0 lanes carry x
  // (k=0..3), all other B elements are EXACT zeros (matches round-3 LDS content).
  f32x4 acc0, acc1, acc2, acc3;
  {
    f32x4 xv = *(const f32x4*)xrow;
    uint4v u;
    u[0] = (grp == 0) ? cvt_pk_bf16(xv[0], xv[1]) : 0u;
    u[1] = (grp == 0) ? cvt_pk_bf16(xv[2], xv[3]) : 0u;
    u[2] = 0; u[3] = 0;
    union { uint4v uu; bf16x8 v; } cst; cst.uu = u;
    acc0 = MFMA(Wx[0], cst.v, c0v[0], 0, 0, 0);
    acc1 = MFMA(Wx[1], cst.v, c0v[1], 0, 0, 0);
    acc2 = MFMA(Wx[2], cst.v, c0v[2], 0, 0, 0);
    acc3 = MFMA(Wx[3], cst.v, c0v[3], 0, 0, 0);
  }

  float c4[4] = {0.f, 0.f, 0.f, 0.f};
  float hl[4] = {0.f, 0.f, 0.f, 0.f};
  __syncthreads();

  for (int t = 0; t < Tlen; ++t) {
    const int cur = t & 1, nxt = cur ^ 1;

    // B fragments of h(t)
    bf16x8 b0 = *(const bf16x8*)&Albuf[cur][m16][ 0 + grp * 8];
    bf16x8 b1 = *(const bf16x8*)&Albuf[cur][m16][32 + grp * 8];
    bf16x8 b2 = *(const bf16x8*)&Albuf[cur][m16][64 + grp * 8];
    bf16x8 b3 = *(const bf16x8*)&Albuf[cur][m16][96 + grp * 8];

    // x(t+1) prefetch (hides under MFMAs; clamped dup-load on final step)
    const int tn = (t + 1 < Tlen) ? (t + 1) : (Tlen - 1);
    f32x4 xv = *(const f32x4*)(xrow + (size_t)tn * Iin);

    // gate chains with interleaved activations (trans overlaps MFMA latency)
    acc0 = MFMA(Wf[0][0], b0, acc0, 0, 0, 0);
    acc0 = MFMA(Wf[0][1], b1, acc0, 0, 0, 0);
    acc0 = MFMA(Wf[0][2], b2, acc0, 0, 0, 0);
    acc0 = MFMA(Wf[0][3], b3, acc0, 0, 0, 0);
    f32x4 si;
#pragma unroll
    for (int r = 0; r < 4; ++r) si[r] = rcp_(1.0f + ex2(-acc0[r]));

    acc1 = MFMA(Wf[1][0], b0, acc1, 0, 0, 0);
    acc1 = MFMA(Wf[1][1], b1, acc1, 0, 0, 0);
    acc1 = MFMA(Wf[1][2], b2, acc1, 0, 0, 0);
    acc1 = MFMA(Wf[1][3], b3, acc1, 0, 0, 0);
    f32x4 sf;
#pragma unroll
    for (int r = 0; r < 4; ++r) sf[r] = rcp_(1.0f + ex2(-acc1[r]));

    acc2 = MFMA(Wf[2][0], b0, acc2, 0, 0, 0);
    acc2 = MFMA(Wf[2][1], b1, acc2, 0, 0, 0);
    acc2 = MFMA(Wf[2][2], b2, acc2, 0, 0, 0);
    acc2 = MFMA(Wf[2][3], b3, acc2, 0, 0, 0);
    f32x4 gt;
#pragma unroll
    for (int r = 0; r < 4; ++r)
      gt[r] = __builtin_fmaf(2.0f, rcp_(1.0f + ex2(-acc2[r])), -1.0f);

    acc3 = MFMA(Wf[3][0], b0, acc3, 0, 0, 0);
    acc3 = MFMA(Wf[3][1], b1, acc3, 0, 0, 0);
    acc3 = MFMA(Wf[3][2], b2, acc3, 0, 0, 0);
    acc3 = MFMA(Wf[3][3], b3, acc3, 0, 0, 0);
    f32x4 so;
#pragma unroll
    for (int r = 0; r < 4; ++r) so[r] = rcp_(1.0f + ex2(-acc3[r]));

    // cell + hidden update (fp32, in registers)
#pragma unroll
    for (int r = 0; r < 4; ++r) {
      float c = __builtin_fmaf(sf[r], c4[r], si[r] * gt[r]);
      c4[r] = c;
      float tc = __builtin_fmaf(
          2.0f, rcp_(1.0f + ex2(-2.8853900817779268f * c)), -1.0f);
      hl[r] = so[r] * tc;
    }

    // pack h(t+1): 4 consecutive hidden cols -> one ds_write_b64
    uint2v hp;
    hp[0] = cvt_pk_bf16(hl[0], hl[1]);
    hp[1] = cvt_pk_bf16(hl[2], hl[3]);

    // re-init acc = bias + Wx @ x(t+1) (register-only; drains during barrier)
    {
      uint4v u;
      u[0] = (grp == 0) ? cvt_pk_bf16(xv[0], xv[1]) : 0u;
      u[1] = (grp == 0) ? cvt_pk_bf16(xv[2], xv[3]) : 0u;
      u[2] = 0; u[3] = 0;
      union { uint4v uu; bf16x8 v; } cst; cst.uu = u;
      acc0 = MFMA(Wx[0], cst.v, c0v[0], 0, 0, 0);
      acc1 = MFMA(Wx[1], cst.v, c0v[1], 0, 0, 0);
      acc2 = MFMA(Wx[2], cst.v, c0v[2], 0, 0, 0);
      acc3 = MFMA(Wx[3], cst.v, c0v[3], 0, 0, 0);
    }

    *(uint2v*)&Albuf[nxt][m16][wid * 16 + grp * 4] = hp;
    __syncthreads();
  }

  // ---- final FC: out = h_T @ W_fc^T + b_fc ----
  {
    f32x4 hv;
    hv[0] = hl[0]; hv[1] = hl[1]; hv[2] = hl[2]; hv[3] = hl[3];
    *(f32x4*)&hfin[m16][wid * 16 + grp * 4] = hv;
  }
  __syncthreads();
  if (tid < 64) {
    const int row = tid >> 2, o = tid & 3;
    float s = b_fc[o];
#pragma unroll 8
    for (int k = 0; k < Hdim; ++k) s += hfin[row][k] * W_fc[o * Hdim + k];
    out[(size_t)(bbase + row) * Odim + o] = s;
  }
}

extern "C" void kernel_launch(void* const* d_in, const int* in_sizes, int n_in,
                              void* d_out, int out_size, void* d_ws, size_t ws_size,
                              hipStream_t stream) {
  const float* x    = (const float*)d_in[0];
  const float* W_ih = (const float*)d_in[1];
  const float* W_hh = (const float*)d_in[2];
  const float* b_ih = (const float*)d_in[3];
  const float* b_hh = (const float*)d_in[4];
  const float* W_fc = (const float*)d_in[5];
  const float* b_fc = (const float*)d_in[6];
  float* out = (float*)d_out;
  lstm_kernel<<<64, 512, 0, stream>>>(x, W_ih, W_hh, b_ih, b_hh, W_fc, b_fc, out);
}